// Round 9
// baseline (93.222 us; speedup 1.0000x reference)
//
#include <hip/hip_runtime.h>

#define BATCH 16
#define HH 512
#define WW 512
#define PLANE (HH*WW)

// Compiler memory-order fences for wave-synchronous LDS exchange.
#define LDS_WAIT()   asm volatile("s_waitcnt lgkmcnt(0)" ::: "memory")
#define WAVE_FENCE() asm volatile("" ::: "memory")

// bf16 pair helpers: word = x in low 16 bits, y in high 16 bits
__device__ __forceinline__ float bf_lo(unsigned u) {
    union { unsigned u; float f; } c; c.u = u << 16; return c.f;
}
__device__ __forceinline__ float bf_hi(unsigned u) {
    union { unsigned u; float f; } c; c.u = u & 0xFFFF0000u; return c.f;
}
__device__ __forceinline__ unsigned f2bf(float f) {   // RTNE, returns low-16 bf16
    union { float f; unsigned u; } c; c.f = f;
    return (c.u + 0x7FFFu + ((c.u >> 16) & 1u)) >> 16;
}
__device__ __forceinline__ unsigned packbf(float x, float y) {
    return f2bf(x) | (f2bf(y) << 16);
}

// ---------------- K1: guide (channel mean) + 15x15 replicate min-pool -> packed bf16 (g,p) ----------------
#define T1 64
#define HALO 7
#define LW (T1 + 2*HALO)   // 78

__global__ __launch_bounds__(256) void k1_guide_minpool(
    const float* __restrict__ smoky, unsigned* __restrict__ gp)
{
    __shared__ float dcp[LW*LW];          // per-pixel channel min, with replicate halo
    __shared__ float vmn[T1*LW];          // vertical 15-min
    __shared__ unsigned short gsh[T1*T1]; // guide (bf16) for interior
    int nwg = gridDim.x;             // 1024, divisible by 8
    int wg = (blockIdx.x & 7) * (nwg >> 3) + (blockIdx.x >> 3);  // XCD-chunked swizzle
    int img  = wg >> 6;              // 64 tiles per image
    int tile = wg & 63;
    int y0 = (tile >> 3) * T1;
    int x0 = (tile & 7) * T1;
    int t = threadIdx.x;
    const float* s0 = smoky + (size_t)img * 3 * PLANE;
    unsigned* gpl = gp + (size_t)img * PLANE;

    for (int i = t; i < LW*LW; i += 256) {
        int ly = i / LW, lx = i - ly * LW;
        int iy = y0 - HALO + ly, ix = x0 - HALO + lx;
        int cy = min(max(iy, 0), HH-1);
        int cx = min(max(ix, 0), WW-1);
        const float* bp = s0 + cy * WW + cx;
        float c0 = bp[0], c1 = bp[PLANE], c2 = bp[2*PLANE];
        dcp[i] = fminf(fminf(c0, c1), c2);
        if (ly >= HALO && ly < HALO+T1 && lx >= HALO && lx < HALO+T1)
            gsh[(ly-HALO)*T1 + (lx-HALO)] = (unsigned short)f2bf((c0 + c1 + c2) * (1.0f/3.0f));
    }
    __syncthreads();
    for (int i = t; i < T1*LW; i += 256) {
        int r = i / LW, c = i - r * LW;
        float m = dcp[r*LW + c];
        #pragma unroll
        for (int d = 1; d < 15; ++d) m = fminf(m, dcp[(r+d)*LW + c]);
        vmn[i] = m;
    }
    __syncthreads();
    for (int i = t; i < T1*T1; i += 256) {
        int r = i >> 6, c = i & 63;
        float m = vmn[r*LW + c];
        #pragma unroll
        for (int d = 1; d < 15; ++d) m = fminf(m, vmn[r*LW + c + d]);
        gpl[(y0+r)*WW + x0 + c] = (unsigned)gsh[r*T1+c] | (f2bf(m) << 16);
    }
}

// ---------------- K2: wave-autonomous fused box sums (I, I^2, p, I*p) -> packed bf16 (a,b) ----------------
// RS=32: row-halo redundancy 47/32 = 1.47x (was 1.94x at RS=16)
#define RS2 32

__global__ __launch_bounds__(256) void k2_ab(
    const unsigned* __restrict__ gp, unsigned* __restrict__ abO)
{
    __shared__ float ls[4][4][80];   // [wave][quantity][slot]
    int nwg = gridDim.x;             // 512
    int wg = (blockIdx.x & 7) * (nwg >> 3) + (blockIdx.x >> 3);
    int w = threadIdx.x >> 6, l = threadIdx.x & 63;
    int gw = wg * 4 + w;             // 0..2047
    int img   = gw >> 7;             // 128 waves per image
    int cg    = (gw >> 4) & 7;
    int strip = gw & 15;
    int y0 = strip * RS2;
    int c0 = cg * 64;
    const unsigned* gpP = gp + (size_t)img * PLANE;
    unsigned* abP = abO + (size_t)img * PLANE;

    // LDS slot s <-> global column c0-7+s
    int col0 = c0 - 7 + l;      // slot l
    int col1 = c0 + 57 + l;     // slot 64+l (lanes 0..13)
    bool v0 = (col0 >= 0);
    bool v1 = (l < 14) && (col1 < WW);

    float sI0=0,sII0=0,sP0=0,sIp0=0;
    float sI1=0,sII1=0,sP1=0,sIp1=0;

    // Branchless row load: clamp row, load unconditionally (per-lane exec masks
    // only), zero by select — VMEM outstanding-count stays path-independent.
    auto loadrow = [&](int y, unsigned& u0, unsigned& u1) {
        int yc = min(max(y, 0), HH-1);
        const unsigned* r = gpP + (size_t)yc * WW;
        unsigned a = 0u, b = 0u;
        if (v0) a = r[col0];
        if (v1) b = r[col1];
        bool rv = ((unsigned)y < (unsigned)HH);
        u0 = rv ? a : 0u;
        u1 = rv ? b : 0u;
    };

    // warm-up: window(y0-1) = rows y0-8 .. y0+6 (15 rows, zero outside)
    for (int r = y0 - 8; r <= y0 + 6; ++r) {
        unsigned u0,u1; loadrow(r, u0,u1);
        float g0=bf_lo(u0), p0=bf_hi(u0), g1=bf_lo(u1), p1=bf_hi(u1);
        sI0+=g0; sII0+=g0*g0; sP0+=p0; sIp0+=g0*p0;
        sI1+=g1; sII1+=g1*g1; sP1+=p1; sIp1+=g1*p1;
    }
    unsigned adA, adB, sbA, sbB;
    loadrow(y0 + 7, adA, adB);   // to add at iter y0
    loadrow(y0 - 8, sbA, sbB);   // to subtract at iter y0

    float* L = &ls[w][0][0];
    const float inv225 = 1.0f/225.0f;
    for (int y = y0; y < y0 + RS2; ++y) {
        // window(y) = window(y-1) + row(y+7) - row(y-8)
        {
            float gA0=bf_lo(adA), pA0=bf_hi(adA), gA1=bf_lo(adB), pA1=bf_hi(adB);
            float gS0=bf_lo(sbA), pS0=bf_hi(sbA), gS1=bf_lo(sbB), pS1=bf_hi(sbB);
            sI0 += gA0-gS0; sII0 += gA0*gA0-gS0*gS0; sP0 += pA0-pS0; sIp0 += gA0*pA0-gS0*pS0;
            sI1 += gA1-gS1; sII1 += gA1*gA1-gS1*gS1; sP1 += pA1-pS1; sIp1 += gA1*pA1-gS1*pS1;
        }
        // prefetch next iteration's rows (in flight during LDS phase)
        loadrow(y + 8, adA, adB);
        loadrow(y - 7, sbA, sbB);
        // wave-private LDS exchange (fenced wave-synchronous pattern)
        L[l] = sI0; L[80+l] = sII0; L[160+l] = sP0; L[240+l] = sIp0;
        if (l < 14) { L[64+l] = sI1; L[144+l] = sII1; L[224+l] = sP1; L[304+l] = sIp1; }
        LDS_WAIT();
        float SI=0,SII=0,SP=0,SIp=0;
        #pragma unroll
        for (int d = 0; d < 15; ++d) {
            SI  += L[l+d];
            SII += L[80+l+d];
            SP  += L[160+l+d];
            SIp += L[240+l+d];
        }
        WAVE_FENCE();   // keep next iter's ds_writes below this iter's ds_reads
        float mI = SI*inv225, mP = SP*inv225;
        float va = (SIp*inv225 - mI*mP) / (SII*inv225 - mI*mI + 1e-3f);
        abP[(size_t)y*WW + c0 + l] = packbf(va, mP - va*mI);
    }
}

// ---------------- K3: wave-autonomous box sums of bf16 (a,b) + guided output + combine ----------------
// guide is recomputed from smoky channels (saves the whole gp read stream).
__global__ __launch_bounds__(256) void k3_final(
    const unsigned* __restrict__ abI,
    const float* __restrict__ smoky, const float* __restrict__ rho,
    float* __restrict__ out)
{
    __shared__ float ls[4][2][80];
    int nwg = gridDim.x;             // 512
    int wg = (blockIdx.x & 7) * (nwg >> 3) + (blockIdx.x >> 3);
    int w = threadIdx.x >> 6, l = threadIdx.x & 63;
    int gw = wg * 4 + w;             // 0..2047
    int img   = gw >> 7;
    int cg    = (gw >> 4) & 7;
    int strip = gw & 15;
    int y0 = strip * RS2;
    int c0 = cg * 64;
    const unsigned* abP = abI + (size_t)img * PLANE;
    const float* sP = smoky + (size_t)img * 3 * PLANE;
    const float* rP = rho   + (size_t)img * 3 * PLANE;
    float* oP = out + (size_t)img * 3 * PLANE;

    int col0 = c0 - 7 + l;
    int col1 = c0 + 57 + l;
    bool v0 = (col0 >= 0);
    bool v1 = (l < 14) && (col1 < WW);

    float sa0=0, sb0=0, sa1=0, sb1=0;

    // Branchless row load (see k2_ab comment).
    auto loadrow = [&](int y, unsigned& u0, unsigned& u1) {
        int yc = min(max(y, 0), HH-1);
        const unsigned* r = abP + (size_t)yc * WW;
        unsigned a = 0u, b = 0u;
        if (v0) a = r[col0];
        if (v1) b = r[col1];
        bool rv = ((unsigned)y < (unsigned)HH);
        u0 = rv ? a : 0u;
        u1 = rv ? b : 0u;
    };

    for (int r = y0 - 8; r <= y0 + 6; ++r) {
        unsigned u0,u1; loadrow(r, u0,u1);
        sa0 += bf_lo(u0); sb0 += bf_hi(u0);
        sa1 += bf_lo(u1); sb1 += bf_hi(u1);
    }
    unsigned adA, adB, sbA, sbB;
    loadrow(y0 + 7, adA, adB);
    loadrow(y0 - 8, sbA, sbB);

    // prefetched emit operands (smoky/rho at current row) — branchless:
    // clamp to the last emitted row (redundant reload on final iter, harmless).
    float es0,es1,es2, er0,er1,er2;
    int yend = y0 + RS2;
    auto loademit = [&](int y) {
        int e = min(y, yend - 1);
        size_t off = (size_t)e*WW + c0 + l;
        es0 = sP[off]; es1 = sP[off+PLANE]; es2 = sP[off+2*PLANE];
        er0 = rP[off]; er1 = rP[off+PLANE]; er2 = rP[off+2*PLANE];
    };
    loademit(y0);

    float* L = &ls[w][0][0];
    const float inv225 = 1.0f/225.0f;
    const float inv11  = 1.0f/1.1f;
    const float third  = 1.0f/3.0f;
    for (int y = y0; y < yend; ++y) {
        sa0 += bf_lo(adA) - bf_lo(sbA);  sb0 += bf_hi(adA) - bf_hi(sbA);
        sa1 += bf_lo(adB) - bf_lo(sbB);  sb1 += bf_hi(adB) - bf_hi(sbB);
        // consume current emit operands into locals
        float s0 = es0, s1 = es1, s2 = es2, r0 = er0, r1 = er1, r2 = er2;
        // guide recomputed from the smoky channels we already loaded (fp32,
        // more accurate than the bf16 gp copy, and saves the gp read stream)
        float g = (s0 + s1 + s2) * third;
        // prefetch next iteration
        loadrow(y + 8, adA, adB);
        loadrow(y - 7, sbA, sbB);
        loademit(y + 1);
        // wave-private LDS exchange (fenced wave-synchronous pattern)
        L[l] = sa0; L[80+l] = sb0;
        if (l < 14) { L[64+l] = sa1; L[144+l] = sb1; }
        LDS_WAIT();
        float SA=0, SB=0;
        #pragma unroll
        for (int d = 0; d < 15; ++d) { SA += L[l+d]; SB += L[80+l+d]; }
        WAVE_FENCE();
        float dcr = SA*inv225*g + SB*inv225;
        float f = (0.1f + dcr) * inv11;
        size_t off = (size_t)y*WW + c0 + l;
        oP[off]          = s0 - f*(1.0f - r0);
        oP[off+PLANE]    = s1 - f*(1.0f - r1);
        oP[off+2*PLANE]  = s2 - f*(1.0f - r2);
    }
}

extern "C" void kernel_launch(void* const* d_in, const int* in_sizes, int n_in,
                              void* d_out, int out_size, void* d_ws, size_t ws_size,
                              hipStream_t stream) {
    const float* smoky = (const float*)d_in[0];
    const float* rho   = (const float*)d_in[1];
    float* out = (float*)d_out;
    const size_t P = (size_t)BATCH * PLANE;
    unsigned* gpbuf = (unsigned*)d_ws;        // packed bf16 (guide,p): P u32
    unsigned* abbuf = (unsigned*)d_ws + P;    // packed bf16 (a,b): P u32

    k1_guide_minpool<<<BATCH*64, 256, 0, stream>>>(smoky, gpbuf);
    k2_ab<<<BATCH*32, 256, 0, stream>>>(gpbuf, abbuf);
    k3_final<<<BATCH*32, 256, 0, stream>>>(abbuf, smoky, rho, out);
}

// Round 10
// 81.863 us; speedup vs baseline: 1.1388x; 1.1388x over previous
//
#include <hip/hip_runtime.h>

#define BATCH 16
#define HH 512
#define WW 512
#define PLANE (HH*WW)

// Compiler memory-order fences for wave-synchronous LDS exchange.
#define LDS_WAIT()   asm volatile("s_waitcnt lgkmcnt(0)" ::: "memory")
#define WAVE_FENCE() asm volatile("" ::: "memory")

// bf16 pair helpers: word = x in low 16 bits, y in high 16 bits
__device__ __forceinline__ float bf_lo(unsigned u) {
    union { unsigned u; float f; } c; c.u = u << 16; return c.f;
}
__device__ __forceinline__ float bf_hi(unsigned u) {
    union { unsigned u; float f; } c; c.u = u & 0xFFFF0000u; return c.f;
}
__device__ __forceinline__ unsigned f2bf(float f) {   // RTNE, returns low-16 bf16
    union { float f; unsigned u; } c; c.f = f;
    return (c.u + 0x7FFFu + ((c.u >> 16) & 1u)) >> 16;
}
__device__ __forceinline__ unsigned packbf(float x, float y) {
    return f2bf(x) | (f2bf(y) << 16);
}
__device__ __forceinline__ float min3f(float a, float b, float c) {
    return fminf(fminf(a, b), c);    // clang fuses to v_min3_f32
}

// ---------------- K1: guide (channel mean) + 15x15 replicate min-pool -> packed bf16 (g,p) ----------------
#define T1 64
#define HALO 7
#define LW (T1 + 2*HALO)   // 78

__global__ __launch_bounds__(256) void k1_guide_minpool(
    const float* __restrict__ smoky, unsigned* __restrict__ gp)
{
    __shared__ float dcp[LW*LW];          // per-pixel channel min, with replicate halo
    __shared__ float vmn[T1*LW];          // vertical 15-min
    __shared__ unsigned short gsh[T1*T1]; // guide (bf16) for interior
    int nwg = gridDim.x;             // 1024, divisible by 8
    int wg = (blockIdx.x & 7) * (nwg >> 3) + (blockIdx.x >> 3);  // XCD-chunked swizzle
    int img  = wg >> 6;              // 64 tiles per image
    int tile = wg & 63;
    int y0 = (tile >> 3) * T1;
    int x0 = (tile & 7) * T1;
    int t = threadIdx.x;
    const float* s0 = smoky + (size_t)img * 3 * PLANE;
    unsigned* gpl = gp + (size_t)img * PLANE;

    for (int i = t; i < LW*LW; i += 256) {
        int ly = i / LW, lx = i - ly * LW;
        int iy = y0 - HALO + ly, ix = x0 - HALO + lx;
        int cy = min(max(iy, 0), HH-1);
        int cx = min(max(ix, 0), WW-1);
        const float* bp = s0 + cy * WW + cx;
        float c0 = bp[0], c1 = bp[PLANE], c2 = bp[2*PLANE];
        dcp[i] = min3f(c0, c1, c2);
        if (ly >= HALO && ly < HALO+T1 && lx >= HALO && lx < HALO+T1)
            gsh[(ly-HALO)*T1 + (lx-HALO)] = (unsigned short)f2bf((c0 + c1 + c2) * (1.0f/3.0f));
    }
    __syncthreads();
    for (int i = t; i < T1*LW; i += 256) {
        int r = i / LW, c = i - r * LW;
        const float* q = &dcp[r*LW + c];
        // 15-tap min as min3 tree (depth 3, 7 ops)
        float m = min3f(min3f(min3f(q[0*LW],q[1*LW],q[2*LW]),
                              min3f(q[3*LW],q[4*LW],q[5*LW]),
                              min3f(q[6*LW],q[7*LW],q[8*LW])),
                        min3f(q[9*LW],q[10*LW],q[11*LW]),
                        min3f(q[12*LW],q[13*LW],q[14*LW]));
        vmn[i] = m;
    }
    __syncthreads();
    for (int i = t; i < T1*T1; i += 256) {
        int r = i >> 6, c = i & 63;
        const float* q = &vmn[r*LW + c];
        float m = min3f(min3f(min3f(q[0],q[1],q[2]),
                              min3f(q[3],q[4],q[5]),
                              min3f(q[6],q[7],q[8])),
                        min3f(q[9],q[10],q[11]),
                        min3f(q[12],q[13],q[14]));
        gpl[(y0+r)*WW + x0 + c] = (unsigned)gsh[r*T1+c] | (f2bf(m) << 16);
    }
}

// ---------------- K2: wave-autonomous fused box sums (I, I^2, p, I*p) -> packed bf16 (a,b) ----------------
#define RS2 16

// balanced-tree 15-tap sum (depth 4) — hipcc can't reassociate FP itself
#define TSUM15(Q) ( (((Q(0)+Q(1))+(Q(2)+Q(3))) + ((Q(4)+Q(5))+(Q(6)+Q(7)))) \
                  + (((Q(8)+Q(9))+(Q(10)+Q(11))) + ((Q(12)+Q(13))+Q(14))) )

__global__ __launch_bounds__(256) void k2_ab(
    const unsigned* __restrict__ gp, unsigned* __restrict__ abO)
{
    __shared__ float ls[4][4][80];   // [wave][quantity][slot]
    int nwg = gridDim.x;             // 1024
    int wg = (blockIdx.x & 7) * (nwg >> 3) + (blockIdx.x >> 3);
    int w = threadIdx.x >> 6, l = threadIdx.x & 63;
    int gw = wg * 4 + w;             // 0..4095
    int img   = gw >> 8;             // 256 waves per image
    int cg    = (gw >> 5) & 7;
    int strip = gw & 31;
    int y0 = strip * RS2;
    int c0 = cg * 64;
    const unsigned* gpP = gp + (size_t)img * PLANE;
    unsigned* abP = abO + (size_t)img * PLANE;

    // LDS slot s <-> global column c0-7+s
    int col0 = c0 - 7 + l;      // slot l
    int col1 = c0 + 57 + l;     // slot 64+l (lanes 0..13)
    bool v0 = (col0 >= 0);
    bool v1 = (l < 14) && (col1 < WW);

    float sI0=0,sII0=0,sP0=0,sIp0=0;
    float sI1=0,sII1=0,sP1=0,sIp1=0;

    // Branchless row load: clamp row, load unconditionally (per-lane exec masks
    // only), zero by select — VMEM outstanding-count stays path-independent.
    auto loadrow = [&](int y, unsigned& u0, unsigned& u1) {
        int yc = min(max(y, 0), HH-1);
        const unsigned* r = gpP + (size_t)yc * WW;
        unsigned a = 0u, b = 0u;
        if (v0) a = r[col0];
        if (v1) b = r[col1];
        bool rv = ((unsigned)y < (unsigned)HH);
        u0 = rv ? a : 0u;
        u1 = rv ? b : 0u;
    };

    // warm-up: window(y0-1) = rows y0-8 .. y0+6 (15 rows, zero outside)
    for (int r = y0 - 8; r <= y0 + 6; ++r) {
        unsigned u0,u1; loadrow(r, u0,u1);
        float g0=bf_lo(u0), p0=bf_hi(u0), g1=bf_lo(u1), p1=bf_hi(u1);
        sI0+=g0; sII0+=g0*g0; sP0+=p0; sIp0+=g0*p0;
        sI1+=g1; sII1+=g1*g1; sP1+=p1; sIp1+=g1*p1;
    }
    unsigned adA, adB, sbA, sbB;
    loadrow(y0 + 7, adA, adB);   // to add at iter y0
    loadrow(y0 - 8, sbA, sbB);   // to subtract at iter y0

    float* L = &ls[w][0][0];
    const float inv225 = 1.0f/225.0f;
    for (int y = y0; y < y0 + RS2; ++y) {
        // window(y) = window(y-1) + row(y+7) - row(y-8)
        {
            float gA0=bf_lo(adA), pA0=bf_hi(adA), gA1=bf_lo(adB), pA1=bf_hi(adB);
            float gS0=bf_lo(sbA), pS0=bf_hi(sbA), gS1=bf_lo(sbB), pS1=bf_hi(sbB);
            sI0 += gA0-gS0; sII0 += gA0*gA0-gS0*gS0; sP0 += pA0-pS0; sIp0 += gA0*pA0-gS0*pS0;
            sI1 += gA1-gS1; sII1 += gA1*gA1-gS1*gS1; sP1 += pA1-pS1; sIp1 += gA1*pA1-gS1*pS1;
        }
        // prefetch next iteration's rows (in flight during LDS phase)
        loadrow(y + 8, adA, adB);
        loadrow(y - 7, sbA, sbB);
        // wave-private LDS exchange (fenced wave-synchronous pattern)
        L[l] = sI0; L[80+l] = sII0; L[160+l] = sP0; L[240+l] = sIp0;
        if (l < 14) { L[64+l] = sI1; L[144+l] = sII1; L[224+l] = sP1; L[304+l] = sIp1; }
        LDS_WAIT();
        #define QI(d)  L[l+(d)]
        #define QII(d) L[80+l+(d)]
        #define QP(d)  L[160+l+(d)]
        #define QIp(d) L[240+l+(d)]
        float SI  = TSUM15(QI);
        float SII = TSUM15(QII);
        float SP  = TSUM15(QP);
        float SIp = TSUM15(QIp);
        #undef QI
        #undef QII
        #undef QP
        #undef QIp
        WAVE_FENCE();   // keep next iter's ds_writes below this iter's ds_reads
        float mI = SI*inv225, mP = SP*inv225;
        float va = (SIp*inv225 - mI*mP) / (SII*inv225 - mI*mI + 1e-3f);
        abP[(size_t)y*WW + c0 + l] = packbf(va, mP - va*mI);
    }
}

// ---------------- K3: wave-autonomous box sums of bf16 (a,b) + guided output + combine ----------------
// guide is recomputed from smoky channels (saves the gp read stream).
__global__ __launch_bounds__(256) void k3_final(
    const unsigned* __restrict__ abI,
    const float* __restrict__ smoky, const float* __restrict__ rho,
    float* __restrict__ out)
{
    __shared__ float ls[4][2][80];
    int nwg = gridDim.x;             // 1024
    int wg = (blockIdx.x & 7) * (nwg >> 3) + (blockIdx.x >> 3);
    int w = threadIdx.x >> 6, l = threadIdx.x & 63;
    int gw = wg * 4 + w;             // 0..4095
    int img   = gw >> 8;
    int cg    = (gw >> 5) & 7;
    int strip = gw & 31;
    int y0 = strip * RS2;
    int c0 = cg * 64;
    const unsigned* abP = abI + (size_t)img * PLANE;
    const float* sP = smoky + (size_t)img * 3 * PLANE;
    const float* rP = rho   + (size_t)img * 3 * PLANE;
    float* oP = out + (size_t)img * 3 * PLANE;

    int col0 = c0 - 7 + l;
    int col1 = c0 + 57 + l;
    bool v0 = (col0 >= 0);
    bool v1 = (l < 14) && (col1 < WW);

    float sa0=0, sb0=0, sa1=0, sb1=0;

    // Branchless row load (see k2_ab comment).
    auto loadrow = [&](int y, unsigned& u0, unsigned& u1) {
        int yc = min(max(y, 0), HH-1);
        const unsigned* r = abP + (size_t)yc * WW;
        unsigned a = 0u, b = 0u;
        if (v0) a = r[col0];
        if (v1) b = r[col1];
        bool rv = ((unsigned)y < (unsigned)HH);
        u0 = rv ? a : 0u;
        u1 = rv ? b : 0u;
    };

    for (int r = y0 - 8; r <= y0 + 6; ++r) {
        unsigned u0,u1; loadrow(r, u0,u1);
        sa0 += bf_lo(u0); sb0 += bf_hi(u0);
        sa1 += bf_lo(u1); sb1 += bf_hi(u1);
    }
    unsigned adA, adB, sbA, sbB;
    loadrow(y0 + 7, adA, adB);
    loadrow(y0 - 8, sbA, sbB);

    // prefetched emit operands (smoky/rho at current row) — branchless:
    // clamp to the last emitted row (redundant reload on final iter, harmless).
    float es0,es1,es2, er0,er1,er2;
    int yend = y0 + RS2;
    auto loademit = [&](int y) {
        int e = min(y, yend - 1);
        size_t off = (size_t)e*WW + c0 + l;
        es0 = sP[off]; es1 = sP[off+PLANE]; es2 = sP[off+2*PLANE];
        er0 = rP[off]; er1 = rP[off+PLANE]; er2 = rP[off+2*PLANE];
    };
    loademit(y0);

    float* L = &ls[w][0][0];
    const float inv225 = 1.0f/225.0f;
    const float inv11  = 1.0f/1.1f;
    const float third  = 1.0f/3.0f;
    for (int y = y0; y < yend; ++y) {
        sa0 += bf_lo(adA) - bf_lo(sbA);  sb0 += bf_hi(adA) - bf_hi(sbA);
        sa1 += bf_lo(adB) - bf_lo(sbB);  sb1 += bf_hi(adB) - bf_hi(sbB);
        // consume current emit operands into locals
        float s0 = es0, s1 = es1, s2 = es2, r0 = er0, r1 = er1, r2 = er2;
        // guide recomputed from the smoky channels we already loaded (fp32,
        // more accurate than the bf16 gp copy, saves the gp read stream)
        float g = (s0 + s1 + s2) * third;
        // prefetch next iteration
        loadrow(y + 8, adA, adB);
        loadrow(y - 7, sbA, sbB);
        loademit(y + 1);
        // wave-private LDS exchange (fenced wave-synchronous pattern)
        L[l] = sa0; L[80+l] = sb0;
        if (l < 14) { L[64+l] = sa1; L[144+l] = sb1; }
        LDS_WAIT();
        #define QA(d) L[l+(d)]
        #define QB(d) L[80+l+(d)]
        float SA = TSUM15(QA);
        float SB = TSUM15(QB);
        #undef QA
        #undef QB
        WAVE_FENCE();
        float dcr = SA*inv225*g + SB*inv225;
        float f = (0.1f + dcr) * inv11;
        size_t off = (size_t)y*WW + c0 + l;
        oP[off]          = s0 - f*(1.0f - r0);
        oP[off+PLANE]    = s1 - f*(1.0f - r1);
        oP[off+2*PLANE]  = s2 - f*(1.0f - r2);
    }
}

extern "C" void kernel_launch(void* const* d_in, const int* in_sizes, int n_in,
                              void* d_out, int out_size, void* d_ws, size_t ws_size,
                              hipStream_t stream) {
    const float* smoky = (const float*)d_in[0];
    const float* rho   = (const float*)d_in[1];
    float* out = (float*)d_out;
    const size_t P = (size_t)BATCH * PLANE;
    unsigned* gpbuf = (unsigned*)d_ws;        // packed bf16 (guide,p): P u32
    unsigned* abbuf = (unsigned*)d_ws + P;    // packed bf16 (a,b): P u32

    k1_guide_minpool<<<BATCH*64, 256, 0, stream>>>(smoky, gpbuf);
    k2_ab<<<BATCH*64, 256, 0, stream>>>(gpbuf, abbuf);
    k3_final<<<BATCH*64, 256, 0, stream>>>(abbuf, smoky, rho, out);
}

// Round 11
// 81.380 us; speedup vs baseline: 1.1455x; 1.0059x over previous
//
#include <hip/hip_runtime.h>

#define BATCH 16
#define HH 512
#define WW 512
#define PLANE (HH*WW)

// Compiler memory-order fences for wave-synchronous LDS exchange.
#define LDS_WAIT()   asm volatile("s_waitcnt lgkmcnt(0)" ::: "memory")
#define WAVE_FENCE() asm volatile("" ::: "memory")

// bf16 pair helpers: word = x in low 16 bits, y in high 16 bits
__device__ __forceinline__ float bf_lo(unsigned u) {
    union { unsigned u; float f; } c; c.u = u << 16; return c.f;
}
__device__ __forceinline__ float bf_hi(unsigned u) {
    union { unsigned u; float f; } c; c.u = u & 0xFFFF0000u; return c.f;
}
__device__ __forceinline__ unsigned f2bf(float f) {   // RTNE, returns low-16 bf16
    union { float f; unsigned u; } c; c.f = f;
    return (c.u + 0x7FFFu + ((c.u >> 16) & 1u)) >> 16;
}
__device__ __forceinline__ unsigned packbf(float x, float y) {
    return f2bf(x) | (f2bf(y) << 16);
}
__device__ __forceinline__ float min3f(float a, float b, float c) {
    return fminf(fminf(a, b), c);    // clang fuses to v_min3_f32
}

// ---------------- K1: guide (channel mean) + 15x15 replicate min-pool -> packed bf16 (g,p) ----------------
#define T1 64
#define HALO 7
#define LW (T1 + 2*HALO)   // 78

__global__ __launch_bounds__(256) void k1_guide_minpool(
    const float* __restrict__ smoky, unsigned* __restrict__ gp)
{
    __shared__ float dcp[LW*LW];          // per-pixel channel min, with replicate halo
    __shared__ float vmn[T1*LW];          // vertical 15-min
    __shared__ unsigned short gsh[T1*T1]; // guide (bf16) for interior
    int nwg = gridDim.x;             // 1024, divisible by 8
    int wg = (blockIdx.x & 7) * (nwg >> 3) + (blockIdx.x >> 3);  // XCD-chunked swizzle
    int img  = wg >> 6;              // 64 tiles per image
    int tile = wg & 63;
    int y0 = (tile >> 3) * T1;
    int x0 = (tile & 7) * T1;
    int t = threadIdx.x;
    const float* s0 = smoky + (size_t)img * 3 * PLANE;
    unsigned* gpl = gp + (size_t)img * PLANE;

    for (int i = t; i < LW*LW; i += 256) {
        int ly = i / LW, lx = i - ly * LW;
        int iy = y0 - HALO + ly, ix = x0 - HALO + lx;
        int cy = min(max(iy, 0), HH-1);
        int cx = min(max(ix, 0), WW-1);
        const float* bp = s0 + cy * WW + cx;
        float c0 = bp[0], c1 = bp[PLANE], c2 = bp[2*PLANE];
        dcp[i] = min3f(c0, c1, c2);
        if (ly >= HALO && ly < HALO+T1 && lx >= HALO && lx < HALO+T1)
            gsh[(ly-HALO)*T1 + (lx-HALO)] = (unsigned short)f2bf((c0 + c1 + c2) * (1.0f/3.0f));
    }
    __syncthreads();
    for (int i = t; i < T1*LW; i += 256) {
        int r = i / LW, c = i - r * LW;
        const float* q = &dcp[r*LW + c];
        float m = min3f(min3f(min3f(q[0*LW],q[1*LW],q[2*LW]),
                              min3f(q[3*LW],q[4*LW],q[5*LW]),
                              min3f(q[6*LW],q[7*LW],q[8*LW])),
                        min3f(q[9*LW],q[10*LW],q[11*LW]),
                        min3f(q[12*LW],q[13*LW],q[14*LW]));
        vmn[i] = m;
    }
    __syncthreads();
    for (int i = t; i < T1*T1; i += 256) {
        int r = i >> 6, c = i & 63;
        const float* q = &vmn[r*LW + c];
        float m = min3f(min3f(min3f(q[0],q[1],q[2]),
                              min3f(q[3],q[4],q[5]),
                              min3f(q[6],q[7],q[8])),
                        min3f(q[9],q[10],q[11]),
                        min3f(q[12],q[13],q[14]));
        gpl[(y0+r)*WW + x0 + c] = (unsigned)gsh[r*T1+c] | (f2bf(m) << 16);
    }
}

// ================= Vectorized column-sliding stages: 128 cols/wave, 8B/lane =================
// LDS layout per quantity: float2 EO[80]; slot i .x = col-sum(col c0-8+2i), .y = col-sum(col c0-7+2i).
// Lane l owns output cols cm=c0+2l, cm+1 -> writes EO[l+4].
// Output col cm needs O[l..l+7] + E[l+1..l+7]; col cm+1 = that - O[l] + E[l+8]:
// 9 lane-stride-1 ds_read_b64 per quantity, conflict-free.
#define RS2 8

__global__ __launch_bounds__(256) void k2_ab(
    const unsigned* __restrict__ gp, unsigned* __restrict__ abO)
{
    __shared__ float2 eo[4][4][80];   // [wave][quantity][slot]
    int nwg = gridDim.x;             // 1024
    int wg = (blockIdx.x & 7) * (nwg >> 3) + (blockIdx.x >> 3);
    int w = threadIdx.x >> 6, l = threadIdx.x & 63;
    int gw = wg * 4 + w;             // 0..4095
    int img   = gw >> 8;             // 256 waves per image
    int cg    = (gw >> 6) & 3;       // 4 column groups of 128
    int strip = gw & 63;             // 64 row-strips of 8
    int y0 = strip * RS2;
    int c0 = cg * 128;
    const unsigned* gpP = gp + (size_t)img * PLANE;
    unsigned* abP = abO + (size_t)img * PLANE;

    int cm = c0 + 2*l;               // main cols cm, cm+1 (always in [0,511])
    int hj = l & 3;
    int hcol  = (l < 4) ? (c0 - 8 + 2*hj) : (c0 + 128 + 2*hj);
    bool hv   = (l < 8) && (hcol >= 0) && (hcol < WW);
    int hslot = (l < 4) ? hj : (68 + hj);

    float sI[2]={0,0}, sII[2]={0,0}, sPv[2]={0,0}, sIp[2]={0,0};
    float hI[2]={0,0}, hII[2]={0,0}, hPv[2]={0,0}, hIp[2]={0,0};

    // Branchless row load (clamped row + select) keeps VMEM counts path-independent.
    auto loadrow = [&](int y, uint2& um, uint2& uh) {
        int yc = min(max(y, 0), HH-1);
        const unsigned* r = gpP + (size_t)yc * WW;
        uint2 a = *reinterpret_cast<const uint2*>(r + cm);
        uint2 b = make_uint2(0u, 0u);
        if (hv) b = *reinterpret_cast<const uint2*>(r + hcol);
        bool rv = ((unsigned)y < (unsigned)HH);
        um.x = rv ? a.x : 0u;  um.y = rv ? a.y : 0u;
        uh.x = rv ? b.x : 0u;  uh.y = rv ? b.y : 0u;
    };

    // warm-up: window(y0-1) = rows y0-8 .. y0+6
    for (int r = y0 - 8; r <= y0 + 6; ++r) {
        uint2 um, uh; loadrow(r, um, uh);
        unsigned mm[2]={um.x,um.y}, hh[2]={uh.x,uh.y};
        #pragma unroll
        for (int k = 0; k < 2; ++k) {
            float g=bf_lo(mm[k]), p=bf_hi(mm[k]);
            sI[k]+=g; sII[k]+=g*g; sPv[k]+=p; sIp[k]+=g*p;
            float gh=bf_lo(hh[k]), ph=bf_hi(hh[k]);
            hI[k]+=gh; hII[k]+=gh*gh; hPv[k]+=ph; hIp[k]+=gh*ph;
        }
    }
    uint2 adM, adH, sbM, sbH;
    loadrow(y0 + 7, adM, adH);
    loadrow(y0 - 8, sbM, sbH);

    float2* EO = &eo[w][0][0];
    const float inv225 = 1.0f/225.0f;
    for (int y = y0; y < y0 + RS2; ++y) {
        {
            unsigned am[2]={adM.x,adM.y}, sm[2]={sbM.x,sbM.y};
            unsigned ah[2]={adH.x,adH.y}, sh[2]={sbH.x,sbH.y};
            #pragma unroll
            for (int k = 0; k < 2; ++k) {
                float gA=bf_lo(am[k]), pA=bf_hi(am[k]);
                float gS=bf_lo(sm[k]), pS=bf_hi(sm[k]);
                sI[k]+=gA-gS; sII[k]+=gA*gA-gS*gS; sPv[k]+=pA-pS; sIp[k]+=gA*pA-gS*pS;
                float gAh=bf_lo(ah[k]), pAh=bf_hi(ah[k]);
                float gSh=bf_lo(sh[k]), pSh=bf_hi(sh[k]);
                hI[k]+=gAh-gSh; hII[k]+=gAh*gAh-gSh*gSh; hPv[k]+=pAh-pSh; hIp[k]+=gAh*pAh-gSh*pSh;
            }
        }
        // prefetch next iteration's rows (in flight during LDS phase)
        loadrow(y + 8, adM, adH);
        loadrow(y - 7, sbM, sbH);
        // wave-private LDS exchange (fenced wave-synchronous pattern)
        EO[l+4]       = make_float2(sI[0],  sI[1]);
        EO[80 + l+4]  = make_float2(sII[0], sII[1]);
        EO[160 + l+4] = make_float2(sPv[0], sPv[1]);
        EO[240 + l+4] = make_float2(sIp[0], sIp[1]);
        if (l < 8) {   // halo slots must be written even when hv==false (zeros = zero-pad)
            EO[hslot]       = make_float2(hI[0],  hI[1]);
            EO[80 + hslot]  = make_float2(hII[0], hII[1]);
            EO[160 + hslot] = make_float2(hPv[0], hPv[1]);
            EO[240 + hslot] = make_float2(hIp[0], hIp[1]);
        }
        LDS_WAIT();
        float S0[4], S1[4];
        #pragma unroll
        for (int q = 0; q < 4; ++q) {
            float2 t[9];
            #pragma unroll
            for (int m = 0; m < 9; ++m) t[m] = EO[q*80 + l + m];
            float so = ((t[0].y+t[1].y)+(t[2].y+t[3].y)) + ((t[4].y+t[5].y)+(t[6].y+t[7].y));
            float se = ((t[1].x+t[2].x)+(t[3].x+t[4].x)) + ((t[5].x+t[6].x)+t[7].x);
            S0[q] = so + se;
            S1[q] = S0[q] - t[0].y + t[8].x;
        }
        WAVE_FENCE();   // keep next iter's ds_writes below this iter's ds_reads
        unsigned pk0, pk1;
        {
            float mI = S0[0]*inv225, mP = S0[2]*inv225;
            float va = (S0[3]*inv225 - mI*mP) / (S0[1]*inv225 - mI*mI + 1e-3f);
            pk0 = packbf(va, mP - va*mI);
        }
        {
            float mI = S1[0]*inv225, mP = S1[2]*inv225;
            float va = (S1[3]*inv225 - mI*mP) / (S1[1]*inv225 - mI*mI + 1e-3f);
            pk1 = packbf(va, mP - va*mI);
        }
        *reinterpret_cast<uint2*>(abP + (size_t)y*WW + cm) = make_uint2(pk0, pk1);
    }
}

// ---------------- K3: vectorized box sums of bf16 (a,b) + guided output + combine ----------------
__global__ __launch_bounds__(256) void k3_final(
    const unsigned* __restrict__ abI,
    const float* __restrict__ smoky, const float* __restrict__ rho,
    float* __restrict__ out)
{
    __shared__ float2 eo[4][2][80];
    int nwg = gridDim.x;             // 1024
    int wg = (blockIdx.x & 7) * (nwg >> 3) + (blockIdx.x >> 3);
    int w = threadIdx.x >> 6, l = threadIdx.x & 63;
    int gw = wg * 4 + w;
    int img   = gw >> 8;
    int cg    = (gw >> 6) & 3;
    int strip = gw & 63;
    int y0 = strip * RS2;
    int c0 = cg * 128;
    const unsigned* abP = abI + (size_t)img * PLANE;
    const float* sP = smoky + (size_t)img * 3 * PLANE;
    const float* rP = rho   + (size_t)img * 3 * PLANE;
    float* oP = out + (size_t)img * 3 * PLANE;

    int cm = c0 + 2*l;
    int hj = l & 3;
    int hcol  = (l < 4) ? (c0 - 8 + 2*hj) : (c0 + 128 + 2*hj);
    bool hv   = (l < 8) && (hcol >= 0) && (hcol < WW);
    int hslot = (l < 4) ? hj : (68 + hj);

    float sa[2]={0,0}, sb[2]={0,0}, ha[2]={0,0}, hb[2]={0,0};

    auto loadrow = [&](int y, uint2& um, uint2& uh) {
        int yc = min(max(y, 0), HH-1);
        const unsigned* r = abP + (size_t)yc * WW;
        uint2 a = *reinterpret_cast<const uint2*>(r + cm);
        uint2 b = make_uint2(0u, 0u);
        if (hv) b = *reinterpret_cast<const uint2*>(r + hcol);
        bool rv = ((unsigned)y < (unsigned)HH);
        um.x = rv ? a.x : 0u;  um.y = rv ? a.y : 0u;
        uh.x = rv ? b.x : 0u;  uh.y = rv ? b.y : 0u;
    };

    for (int r = y0 - 8; r <= y0 + 6; ++r) {
        uint2 um, uh; loadrow(r, um, uh);
        sa[0]+=bf_lo(um.x); sb[0]+=bf_hi(um.x);
        sa[1]+=bf_lo(um.y); sb[1]+=bf_hi(um.y);
        ha[0]+=bf_lo(uh.x); hb[0]+=bf_hi(uh.x);
        ha[1]+=bf_lo(uh.y); hb[1]+=bf_hi(uh.y);
    }
    uint2 adM, adH, sbM, sbH;
    loadrow(y0 + 7, adM, adH);
    loadrow(y0 - 8, sbM, sbH);

    // prefetched emit operands (smoky/rho float2 at current row), branchless clamp
    float2 es0, es1, es2, er0, er1, er2;
    int yend = y0 + RS2;
    auto loademit = [&](int y) {
        int e = min(y, yend - 1);
        size_t off = (size_t)e*WW + cm;
        es0 = *reinterpret_cast<const float2*>(sP + off);
        es1 = *reinterpret_cast<const float2*>(sP + off + PLANE);
        es2 = *reinterpret_cast<const float2*>(sP + off + 2*PLANE);
        er0 = *reinterpret_cast<const float2*>(rP + off);
        er1 = *reinterpret_cast<const float2*>(rP + off + PLANE);
        er2 = *reinterpret_cast<const float2*>(rP + off + 2*PLANE);
    };
    loademit(y0);

    float2* EO = &eo[w][0][0];
    const float inv225 = 1.0f/225.0f;
    const float inv11  = 1.0f/1.1f;
    const float third  = 1.0f/3.0f;
    for (int y = y0; y < yend; ++y) {
        sa[0] += bf_lo(adM.x) - bf_lo(sbM.x);  sb[0] += bf_hi(adM.x) - bf_hi(sbM.x);
        sa[1] += bf_lo(adM.y) - bf_lo(sbM.y);  sb[1] += bf_hi(adM.y) - bf_hi(sbM.y);
        ha[0] += bf_lo(adH.x) - bf_lo(sbH.x);  hb[0] += bf_hi(adH.x) - bf_hi(sbH.x);
        ha[1] += bf_lo(adH.y) - bf_lo(sbH.y);  hb[1] += bf_hi(adH.y) - bf_hi(sbH.y);
        // consume current emit operands into locals
        float2 cs0 = es0, cs1 = es1, cs2 = es2, cr0 = er0, cr1 = er1, cr2 = er2;
        // prefetch next iteration
        loadrow(y + 8, adM, adH);
        loadrow(y - 7, sbM, sbH);
        loademit(y + 1);
        // wave-private LDS exchange
        EO[l+4]      = make_float2(sa[0], sa[1]);
        EO[80 + l+4] = make_float2(sb[0], sb[1]);
        if (l < 8) {
            EO[hslot]      = make_float2(ha[0], ha[1]);
            EO[80 + hslot] = make_float2(hb[0], hb[1]);
        }
        LDS_WAIT();
        float SA0, SA1, SB0, SB1;
        {
            float2 t[9];
            #pragma unroll
            for (int m = 0; m < 9; ++m) t[m] = EO[l + m];
            float so = ((t[0].y+t[1].y)+(t[2].y+t[3].y)) + ((t[4].y+t[5].y)+(t[6].y+t[7].y));
            float se = ((t[1].x+t[2].x)+(t[3].x+t[4].x)) + ((t[5].x+t[6].x)+t[7].x);
            SA0 = so + se;  SA1 = SA0 - t[0].y + t[8].x;
        }
        {
            float2 t[9];
            #pragma unroll
            for (int m = 0; m < 9; ++m) t[m] = EO[80 + l + m];
            float so = ((t[0].y+t[1].y)+(t[2].y+t[3].y)) + ((t[4].y+t[5].y)+(t[6].y+t[7].y));
            float se = ((t[1].x+t[2].x)+(t[3].x+t[4].x)) + ((t[5].x+t[6].x)+t[7].x);
            SB0 = so + se;  SB1 = SB0 - t[0].y + t[8].x;
        }
        WAVE_FENCE();
        float g0 = (cs0.x + cs1.x + cs2.x) * third;
        float g1 = (cs0.y + cs1.y + cs2.y) * third;
        float f0 = (0.1f + SA0*inv225*g0 + SB0*inv225) * inv11;
        float f1 = (0.1f + SA1*inv225*g1 + SB1*inv225) * inv11;
        size_t off = (size_t)y*WW + cm;
        float2 o0, o1, o2;
        o0.x = cs0.x - f0*(1.0f - cr0.x);  o0.y = cs0.y - f1*(1.0f - cr0.y);
        o1.x = cs1.x - f0*(1.0f - cr1.x);  o1.y = cs1.y - f1*(1.0f - cr1.y);
        o2.x = cs2.x - f0*(1.0f - cr2.x);  o2.y = cs2.y - f1*(1.0f - cr2.y);
        *reinterpret_cast<float2*>(oP + off)           = o0;
        *reinterpret_cast<float2*>(oP + off + PLANE)   = o1;
        *reinterpret_cast<float2*>(oP + off + 2*PLANE) = o2;
    }
}

extern "C" void kernel_launch(void* const* d_in, const int* in_sizes, int n_in,
                              void* d_out, int out_size, void* d_ws, size_t ws_size,
                              hipStream_t stream) {
    const float* smoky = (const float*)d_in[0];
    const float* rho   = (const float*)d_in[1];
    float* out = (float*)d_out;
    const size_t P = (size_t)BATCH * PLANE;
    unsigned* gpbuf = (unsigned*)d_ws;        // packed bf16 (guide,p): P u32
    unsigned* abbuf = (unsigned*)d_ws + P;    // packed bf16 (a,b): P u32

    k1_guide_minpool<<<BATCH*64, 256, 0, stream>>>(smoky, gpbuf);
    k2_ab<<<BATCH*64, 256, 0, stream>>>(gpbuf, abbuf);
    k3_final<<<BATCH*64, 256, 0, stream>>>(abbuf, smoky, rho, out);
}